// Round 5
// baseline (315.623 us; speedup 1.0000x reference)
//
#include <hip/hip_runtime.h>
#include <hip/hip_bf16.h>

#define GAT_ALPHA 0.2f

typedef short bf16x8 __attribute__((ext_vector_type(8)));
typedef float f32x4 __attribute__((ext_vector_type(4)));

__device__ __forceinline__ unsigned f2bf_u(float x) {
  union { float f; unsigned u; } v; v.f = x;
  return (v.u + 0x7fffu + ((v.u >> 16) & 1u)) >> 16;  // RNE to bf16
}
__device__ __forceinline__ unsigned short f2bf(float x) { return (unsigned short)f2bf_u(x); }

// ---------------- kernel 0: W (512x256 f32) -> WT bf16 (256x512) ----------
__global__ void k_wt(const float* __restrict__ W, unsigned short* __restrict__ WT) {
  int kb = blockIdx.x * 8;       // 64 blocks
  int f = threadIdx.x;           // 256 threads = one f each
  bf16x8 o;
#pragma unroll
  for (int i = 0; i < 8; ++i) o[i] = (short)f2bf(W[(kb + i) * 256 + f]);
  *reinterpret_cast<bf16x8*>(WT + f * 512 + kb) = o;
}

// ---------------- kernel P: adj (int32 0/1) -> bitmap bytes ---------------
// bm[row][256] with byte position (j&15)*16 + (j>>4) for byte-col j, so a
// k_gat thread (fixed K=j&15) reads its 16 chunk-bytes as one contiguous 16B.
// Grid 2048 x 256 thr: block = 8 rows. Pure HBM stream (128 MB read, 4 MB w).
__global__ __launch_bounds__(256) void k_pack(const int* __restrict__ adj,
                                              unsigned char* __restrict__ bm) {
  __shared__ unsigned char sb[2048];
  const int bId = blockIdx.x, t = threadIdx.x;
  const int4* base = reinterpret_cast<const int4*>(adj + (size_t)bId * 8 * 2048);
#pragma unroll
  for (int i = 0; i < 8; ++i) {
    int4 v0 = base[i * 512 + t * 2];
    int4 v1 = base[i * 512 + t * 2 + 1];
    unsigned by = (v0.x != 0)        | ((v0.y != 0) << 1) | ((v0.z != 0) << 2) |
                  ((v0.w != 0) << 3) | ((v1.x != 0) << 4) | ((v1.y != 0) << 5) |
                  ((v1.z != 0) << 6) | ((v1.w != 0) << 7);
    sb[i * 256 + (t & 15) * 16 + (t >> 4)] = (unsigned char)by;
  }
  __syncthreads();
  reinterpret_cast<uint2*>(bm + (size_t)bId * 2048)[t] =
      reinterpret_cast<const uint2*>(sb)[t];
}

// ---------------- kernel 1: WhT = (h@W)^T bf16 [b][f][n], + exp(f1/f2) ----
// Grid 1024 (8 b x 128 node-groups of 16), 256 thr, VGPR<=128 -> 4 blocks/CU.
// Wave tile: 64 f x 16 n. h register pipeline depth-3 (HBM latency ~900cyc).
__global__ __launch_bounds__(256, 4) void k_gemm1(
    const float* __restrict__ h, const unsigned short* __restrict__ WT,
    const float* __restrict__ avec,
    unsigned short* __restrict__ WhT,
    float* __restrict__ E1p, float* __restrict__ E1n,
    float* __restrict__ E2p, float* __restrict__ E2n)
{
  const int bx = blockIdx.x;
  const int b = bx & 7, ng = bx >> 3;
  const int n0 = ng * 16;
  const int t = threadIdx.x;
  const int lane = t & 63, w = t >> 6;
  const int l15 = lane & 15, q = lane >> 4;

  __shared__ __align__(16) unsigned short Wt[256 * 24];  // 12 KB, 16B-aligned rows
  __shared__ float f1a[16], f2a[16];
  if (t < 16) { f1a[t] = 0.f; f2a[t] = 0.f; }

  f32x4 acc[4];
#pragma unroll
  for (int i = 0; i < 4; ++i) acc[i] = (f32x4){0.f, 0.f, 0.f, 0.f};

  const unsigned short* wtb = WT + (w * 64 + l15) * 512 + q * 8;
  const float* hrow = h + ((size_t)(b * 2048 + n0 + l15)) * 512 + q * 8;

  // h pipeline prologue: stages k=0,1,2
  float4 hS0[2], hS1[2], hS2[2];
  hS0[0] = *reinterpret_cast<const float4*>(hrow);
  hS0[1] = *reinterpret_cast<const float4*>(hrow + 4);
  hS1[0] = *reinterpret_cast<const float4*>(hrow + 32);
  hS1[1] = *reinterpret_cast<const float4*>(hrow + 36);
  hS2[0] = *reinterpret_cast<const float4*>(hrow + 64);
  hS2[1] = *reinterpret_cast<const float4*>(hrow + 68);

#pragma unroll
  for (int k = 0; k < 16; ++k) {
    // WT fragments for step k (L2-hot, consumed ~this step)
    bf16x8 af[4];
#pragma unroll
    for (int mt = 0; mt < 4; ++mt)
      af[mt] = *reinterpret_cast<const bf16x8*>(wtb + mt * 16 * 512 + k * 32);
    // issue h(k+3)
    float4 hN[2];
    if (k < 13) {
      hN[0] = *reinterpret_cast<const float4*>(hrow + (k + 3) * 32);
      hN[1] = *reinterpret_cast<const float4*>(hrow + (k + 3) * 32 + 4);
    }
    // convert h(k), MFMA
    bf16x8 bb;
    {
      float4 x0 = hS0[0], x1 = hS0[1];
      bb[0] = (short)f2bf(x0.x); bb[1] = (short)f2bf(x0.y);
      bb[2] = (short)f2bf(x0.z); bb[3] = (short)f2bf(x0.w);
      bb[4] = (short)f2bf(x1.x); bb[5] = (short)f2bf(x1.y);
      bb[6] = (short)f2bf(x1.z); bb[7] = (short)f2bf(x1.w);
    }
#pragma unroll
    for (int mt = 0; mt < 4; ++mt)
      acc[mt] = __builtin_amdgcn_mfma_f32_16x16x32_bf16(af[mt], bb, acc[mt], 0, 0, 0);
    // rotate h stages
    hS0[0] = hS1[0]; hS0[1] = hS1[1];
    hS1[0] = hS2[0]; hS1[1] = hS2[1];
    if (k < 13) { hS2[0] = hN[0]; hS2[1] = hN[1]; }
  }

  // epilogue: C row f = w*64+mt*16+q*4+r, col n = l15
  float s1 = 0.f, s2 = 0.f;
#pragma unroll
  for (int mt = 0; mt < 4; ++mt) {
#pragma unroll
    for (int r = 0; r < 4; ++r) {
      int f = w * 64 + mt * 16 + q * 4 + r;
      float v = acc[mt][r];
      Wt[f * 24 + l15] = f2bf(v);
      s1 += v * avec[f];
      s2 += v * avec[256 + f];
    }
  }
  s1 += __shfl_xor(s1, 16); s1 += __shfl_xor(s1, 32);
  s2 += __shfl_xor(s2, 16); s2 += __shfl_xor(s2, 32);
  __syncthreads();   // Wt visible, f1a init visible
  if (q == 0) {
    atomicAdd(&f1a[l15], s1);
    atomicAdd(&f2a[l15], s2);
  }
  // WhT store: thread t = f-row, 32 B contiguous
  {
    uint4 va = *reinterpret_cast<const uint4*>(Wt + t * 24);
    uint4 vb = *reinterpret_cast<const uint4*>(Wt + t * 24 + 8);
    unsigned short* dst = WhT + (size_t)(b * 256 + t) * 2048 + n0;
    *reinterpret_cast<uint4*>(dst) = va;
    *reinterpret_cast<uint4*>(dst + 8) = vb;
  }
  __syncthreads();   // atomics complete
  if (t < 16) {
    int n = b * 2048 + n0 + t;
    float f1 = f1a[t], f2 = f2a[t];
    E1p[n] = __expf(f1);
    E1n[n] = __expf(GAT_ALPHA * f1);
    E2p[n] = __expf(f2);
    E2n[n] = __expf(GAT_ALPHA * f2);
  }
}

// build one A-fragment (8 cols of one row) from a bitmap byte
__device__ __forceinline__ void build_frag(
    unsigned short* dst, unsigned by, float e1p, float e1n,
    float4 epl, float4 eph, float4 enl, float4 enh, float& den)
{
  float p0 = (by & 1u)   ? fmaxf(e1p * epl.x, e1n * enl.x) : 0.f;
  float p1 = (by & 2u)   ? fmaxf(e1p * epl.y, e1n * enl.y) : 0.f;
  float p2 = (by & 4u)   ? fmaxf(e1p * epl.z, e1n * enl.z) : 0.f;
  float p3 = (by & 8u)   ? fmaxf(e1p * epl.w, e1n * enl.w) : 0.f;
  float p4 = (by & 16u)  ? fmaxf(e1p * eph.x, e1n * enh.x) : 0.f;
  float p5 = (by & 32u)  ? fmaxf(e1p * eph.y, e1n * enh.y) : 0.f;
  float p6 = (by & 64u)  ? fmaxf(e1p * eph.z, e1n * enh.z) : 0.f;
  float p7 = (by & 128u) ? fmaxf(e1p * eph.w, e1n * enh.w) : 0.f;
  den += ((p0 + p1) + (p2 + p3)) + ((p4 + p5) + (p6 + p7));
  uint4 pk;
  pk.x = f2bf_u(p0) | (f2bf_u(p1) << 16);
  pk.y = f2bf_u(p2) | (f2bf_u(p3) << 16);
  pk.z = f2bf_u(p4) | (f2bf_u(p5) << 16);
  pk.w = f2bf_u(p6) | (f2bf_u(p7) << 16);
  *reinterpret_cast<uint4*>(dst) = pk;
}

// ---------------- kernel 2: out = elu(softmax-masked P @ Wh), fused -------
// Grid 256 (8 b x 32 row-groups of 64), 512 thr, VGPR<=128 -> 2 blocks/CU.
// K-loop has NO HBM dependence: adj bits from bitmap bytes (L1-hot, 1-chunk
// lookahead), e2 L1-hot, B-fragments from XCD-L2-resident WhT. The barrier
// drain is ~L2 latency, not HBM.
__global__ __launch_bounds__(512, 4) void k_gat(
    const unsigned char* __restrict__ bm, const unsigned short* __restrict__ WhT,
    const float* __restrict__ E1p, const float* __restrict__ E1n,
    const float* __restrict__ E2p, const float* __restrict__ E2n,
    float* __restrict__ out)
{
  const int bx = blockIdx.x;               // 256 blocks = 8 batches x 32 row-groups
  const int b = bx & 7, ig = bx >> 3;
  const int i0 = ig * 64;
  const int t = threadIdx.x;
  const int lane = t & 63, w = t >> 6;
  const int l15 = lane & 15, q = lane >> 4;
  const int m = t & 15, qk = (t >> 4) & 3, pp = t >> 6;
  const int rt0 = pp >> 2, ks = pp & 3;
  const int r0 = rt0 * 16 + m, r1 = r0 + 32;
  const int cb = ks * 32 + qk * 8;
  const int K = ks * 4 + qk;               // byte-column within a chunk

  __shared__ __align__(16) unsigned short Pb[2][8192];  // 16 frags x 64 lanes x 16B
  __shared__ float den_l[64];
  if (t < 64) den_l[t] = 0.f;

  const float e1p0 = E1p[b * 2048 + i0 + r0], e1n0 = E1n[b * 2048 + i0 + r0];
  const float e1p1 = E1p[b * 2048 + i0 + r1], e1n1 = E1n[b * 2048 + i0 + r1];
  float d0 = 0.f, d1 = 0.f;

  f32x4 acc[4][2];
#pragma unroll
  for (int i = 0; i < 4; ++i)
#pragma unroll
    for (int j = 0; j < 2; ++j) acc[i][j] = (f32x4){0.f, 0.f, 0.f, 0.f};

  const unsigned char* bm0 = bm + ((size_t)(b * 2048 + i0 + r0)) * 256 + K * 16;
  const unsigned char* bm1 = bm0 + (size_t)32 * 256;
  const int e2b = b * 2048 + cb;
  const unsigned short* Wb = WhT + (size_t)(b * 256 + w * 32) * 2048;

  // ---- prologue: construct chunk 0
  {
    unsigned by0 = bm0[0], by1 = bm1[0];
    float4 epl = *reinterpret_cast<const float4*>(E2p + e2b);
    float4 eph = *reinterpret_cast<const float4*>(E2p + e2b + 4);
    float4 enl = *reinterpret_cast<const float4*>(E2n + e2b);
    float4 enh = *reinterpret_cast<const float4*>(E2n + e2b + 4);
    build_frag(&Pb[0][(pp * 64 + lane) * 8], by0, e1p0, e1n0, epl, eph, enl, enh, d0);
    build_frag(&Pb[0][((pp + 8) * 64 + lane) * 8], by1, e1p1, e1n1, epl, eph, enl, enh, d1);
  }
  __syncthreads();

#pragma unroll 2
  for (int c = 0; c < 16; ++c) {
    // 1. issue B(c) (XCD-L2, consumed at MFMA ~200+ cyc later)
    bf16x8 bcur[2][4];
#pragma unroll
    for (int ct = 0; ct < 2; ++ct)
#pragma unroll
      for (int k2 = 0; k2 < 4; ++k2)
        bcur[ct][k2] = *reinterpret_cast<const bf16x8*>(
            Wb + (size_t)(ct * 16 + l15) * 2048 + c * 128 + k2 * 32 + q * 8);
    // 2. issue bytes + e2 for chunk c+1 (L1-hot, consumed in construct)
    unsigned nby0 = 0, nby1 = 0;
    float4 nEpl, nEph, nEnl, nEnh;
    if (c < 15) {
      nby0 = bm0[c + 1];
      nby1 = bm1[c + 1];
      int o = (c + 1) * 128;
      nEpl = *reinterpret_cast<const float4*>(E2p + e2b + o);
      nEph = *reinterpret_cast<const float4*>(E2p + e2b + o + 4);
      nEnl = *reinterpret_cast<const float4*>(E2n + e2b + o);
      nEnh = *reinterpret_cast<const float4*>(E2n + e2b + o + 4);
    }
    // 3. MFMA(c): A-frags from LDS (conflict-free b128), B from registers
    const unsigned short* pb = &Pb[c & 1][0];
#pragma unroll
    for (int k2 = 0; k2 < 4; ++k2) {
      bf16x8 afr[4];
#pragma unroll
      for (int rt = 0; rt < 4; ++rt)
        afr[rt] = *reinterpret_cast<const bf16x8*>(pb + ((rt * 4 + k2) * 64 + lane) * 8);
#pragma unroll
      for (int rt = 0; rt < 4; ++rt)
#pragma unroll
        for (int ct = 0; ct < 2; ++ct)
          acc[rt][ct] = __builtin_amdgcn_mfma_f32_16x16x32_bf16(afr[rt], bcur[ct][k2], acc[rt][ct], 0, 0, 0);
    }
    // 4. construct(c+1) into the other buffer
    if (c < 15) {
      unsigned short* wb = &Pb[(c + 1) & 1][0];
      build_frag(wb + (pp * 64 + lane) * 8, nby0, e1p0, e1n0, nEpl, nEph, nEnl, nEnh, d0);
      build_frag(wb + ((pp + 8) * 64 + lane) * 8, nby1, e1p1, e1n1, nEpl, nEph, nEnl, nEnh, d1);
      __syncthreads();
    }
  }

  // denominator: reduce over qk lanes, then 4 row-tile waves combine via LDS
  d0 += __shfl_xor(d0, 16); d0 += __shfl_xor(d0, 32);
  d1 += __shfl_xor(d1, 16); d1 += __shfl_xor(d1, 32);
  if (lane < 16) {
    atomicAdd(&den_l[r0], d0);
    atomicAdd(&den_l[r1], d1);
  }
  __syncthreads();

  // epilogue: out = elu(acc/den); C row = rt*16+q*4+r, col f = w*32+ct*16+l15
#pragma unroll
  for (int rt = 0; rt < 4; ++rt) {
#pragma unroll
    for (int r = 0; r < 4; ++r) {
      int row = rt * 16 + q * 4 + r;
      float dinv = 1.0f / den_l[row];
      size_t ob = ((size_t)(b * 2048 + i0 + row)) * 256 + w * 32;
#pragma unroll
      for (int ct = 0; ct < 2; ++ct) {
        float v = acc[rt][ct][r] * dinv;
        v = v > 0.f ? v : (__expf(v) - 1.f);
        out[ob + ct * 16 + l15] = v;
      }
    }
  }
}

extern "C" void kernel_launch(void* const* d_in, const int* in_sizes, int n_in,
                              void* d_out, int out_size, void* d_ws, size_t ws_size,
                              hipStream_t stream) {
  const float* h   = (const float*)d_in[0];   // [8,2048,512] f32
  const int*   adj = (const int*)d_in[1];     // [8,2048,2048] i32
  const float* W   = (const float*)d_in[2];   // [512,256] f32
  const float* a   = (const float*)d_in[3];   // [512,1] f32
  float* out = (float*)d_out;                 // [8,2048,256] f32

  char* ws = (char*)d_ws;
  unsigned short* WhT = (unsigned short*)ws;                  // 8 MB   [8][256][2048] bf16
  unsigned short* WT  = (unsigned short*)(ws + 8388608);      // 256 KB [256][512] bf16
  float* E1p = (float*)(ws + 8388608 + 262144);               // 64 KB each
  float* E1n = E1p + 16384;
  float* E2p = E1n + 16384;
  float* E2n = E2p + 16384;
  unsigned char* bm = (unsigned char*)(ws + 8388608 + 262144 + 4 * 65536);  // 4 MB

  k_wt<<<dim3(64), dim3(256), 0, stream>>>(W, WT);
  k_pack<<<dim3(2048), dim3(256), 0, stream>>>(adj, bm);
  k_gemm1<<<dim3(1024), dim3(256), 0, stream>>>(h, WT, a, WhT, E1p, E1n, E2p, E2n);
  k_gat<<<dim3(256), dim3(512), 0, stream>>>(bm, WhT, E1p, E1n, E2p, E2n, out);
}